// Round 7
// baseline (376.759 us; speedup 1.0000x reference)
//
#include <hip/hip_runtime.h>
#include <math.h>

#define NPTS 8192
#define KNN  20
#define NCELL 4096          // 16^3 Morton cells
#define GLO  (-4.0f)
#define GH   (0.5f)
#define GINV (2.0f)

__device__ __forceinline__ int cellof(float v) {
    int c = (int)floorf((v - GLO) * GINV);
    return min(max(c, 0), 15);
}
__device__ __forceinline__ int spread4(int b) {
    return (b & 1) | ((b & 2) << 2) | ((b & 4) << 4) | ((b & 8) << 6);
}

// 64-lane bitonic sort, ascending by lane. Keys d, payload ji.
__device__ __forceinline__ void bitonic64(float& d, int& ji, int lane) {
#pragma unroll
    for (int k = 2; k <= 64; k <<= 1) {
#pragma unroll
        for (int j = k >> 1; j > 0; j >>= 1) {
            const float od = __shfl_xor(d, j);
            const int   oi = __shfl_xor(ji, j);
            const bool up      = ((lane & k) == 0);
            const bool lower   = ((lane & j) == 0);
            const bool takeMin = (up == lower);
            const bool sw = takeMin ? (od < d) : (od > d);
            d  = sw ? od : d;
            ji = sw ? oi : ji;
        }
    }
}

__device__ __forceinline__ void bitonic_clean64(float& d, int& ji, int lane) {
#pragma unroll
    for (int j = 32; j > 0; j >>= 1) {
        const float od = __shfl_xor(d, j);
        const int   oi = __shfl_xor(ji, j);
        const bool lower = ((lane & j) == 0);
        const bool sw = lower ? (od < d) : (od > d);
        d  = sw ? od : d;
        ji = sw ? oi : ji;
    }
}

// merge LDS hit-pool (cnt entries) into the resident sorted-64 list (ld,lj)
__device__ __forceinline__ void compact(float& ld, int& lj,
                                        const float* __restrict__ sd,
                                        const int* __restrict__ sj,
                                        int cnt, int lane) {
    __builtin_amdgcn_wave_barrier();
    float bd = (lane < cnt) ? sd[lane] : INFINITY;
    int   bj = (lane < cnt) ? sj[lane] : -1;
    bitonic64(bd, bj, lane);
    const float rd = __shfl(bd, 63 - lane);
    const int   rj = __shfl(bj, 63 - lane);
    const bool sw = rd < ld;
    float md = sw ? rd : ld;
    int   mj = sw ? rj : lj;
    bitonic_clean64(md, mj, lane);
    ld = md; lj = mj;
}

// ---------------- fused prep: xq + Morton cell id + hist + Wc0/1/2 ----------------
__device__ __forceinline__ void prep_w_elem(const float* __restrict__ W,
                                            float* __restrict__ Wc,
                                            int tid, int O, int C) {
    const int o = tid / C, k = tid % C;
    const float wa = W[o*2*C + k];
    const float wb = W[o*2*C + C + k];
    Wc[o*C + k]       = wa - wb;
    Wc[(O + o)*C + k] = wb;
}

__global__ void prep_all(const float* __restrict__ x,
                         const float* __restrict__ W0,
                         const float* __restrict__ W1,
                         const float* __restrict__ W2,
                         float4* __restrict__ xq,
                         int* __restrict__ bId,
                         int* __restrict__ hist,
                         float* __restrict__ Wc0,
                         float* __restrict__ Wc1,
                         float* __restrict__ Wc2) {
    const int bid = blockIdx.x;
    const int t = threadIdx.x;
    if (bid < 32) {
        const int i = bid * 256 + t;
        const float a = x[3*i+0], b = x[3*i+1], c = x[3*i+2];
        xq[i] = make_float4(a, b, c, 0.0f);
        const int cell = spread4(cellof(a)) | (spread4(cellof(b)) << 1)
                       | (spread4(cellof(c)) << 2);
        bId[i] = cell;
        atomicAdd(&hist[cell], 1);
    } else if (bid == 32) {
        if (t < 192) prep_w_elem(W0, Wc0, t, 64, 3);
    } else if (bid < 65) {
        prep_w_elem(W1, Wc1, (bid - 33) * 256 + t, 128, 64);
    } else {
        prep_w_elem(W2, Wc2, (bid - 65) * 256 + t, 256, 128);
    }
}

// ---------------- exclusive prefix over 4096 cells (1 block, 4/thread) ----------------
__global__ __launch_bounds__(1024) void prefix4096(const int* __restrict__ hist,
                                                   int* __restrict__ cstart,
                                                   int* __restrict__ work) {
    __shared__ int s[1024];
    const int t = threadIdx.x;
    const int4 v = *reinterpret_cast<const int4*>(&hist[t * 4]);
    const int s0 = v.x, s1 = s0 + v.y, s2 = s1 + v.z, s3 = s2 + v.w;
    s[t] = s3;
    __syncthreads();
    for (int off = 1; off < 1024; off <<= 1) {
        const int u = (t >= off) ? s[t - off] : 0;
        __syncthreads();
        s[t] += u;
        __syncthreads();
    }
    const int excl = s[t] - s3;
    cstart[t*4+0] = excl;      work[t*4+0] = excl;
    cstart[t*4+1] = excl + s0; work[t*4+1] = excl + s0;
    cstart[t*4+2] = excl + s1; work[t*4+2] = excl + s1;
    cstart[t*4+3] = excl + s2; work[t*4+3] = excl + s2;
    if (t == 0) cstart[NCELL] = NPTS;
}

// ---------------- per-point scatter into Morton-sorted order ----------------
__global__ __launch_bounds__(256) void scatter_pts(const float4* __restrict__ xq,
                                                   const int* __restrict__ bId,
                                                   int* __restrict__ work,
                                                   float4* __restrict__ srt) {
    const int i = blockIdx.x * 256 + threadIdx.x;
    const int pos = atomicAdd(&work[bId[i]], 1);
    float4 v = xq[i];
    v.w = __int_as_float(i);
    srt[pos] = v;
}

// ---------------- KNN: Morton-block init + analytic cell-box search ----------------
// 1 query/wave. Init top-64 from own sorted 64-block (spatially compact).
// Scan own cell, compact -> tight cm; then raster cells in [q +- r] box with
// analytic AABB pruning (edge cells get infinite extent for clamped outliers).
// Init-block positions masked out of all scans (no duplicates). Exact.
__global__ __launch_bounds__(256) void knn_cell(const float4* __restrict__ srt,
                                                const int* __restrict__ cstart,
                                                int* __restrict__ idx_out) {
    __shared__ float sdp[4][64];
    __shared__ int   sjp[4][64];
    const int lane = threadIdx.x & 63;
    const int wv   = threadIdx.x >> 6;
    const int s    = blockIdx.x * 4 + wv;
    float* sd = sdp[wv];
    int*   sj = sjp[wv];

    const float4 me = srt[s];
    const int qorig = __float_as_int(me.w);
    const int base = (s >> 6) << 6;         // own 64-block start

    // init: own sorted block (contains self, d=0)
    float ld, cm;
    int lj;
    {
        const float4 c = srt[base + lane];
        const float dx = me.x - c.x, dy = me.y - c.y, dz = me.z - c.z;
        ld = dx*dx + dy*dy + dz*dz;
        lj = __float_as_int(c.w);
        bitonic64(ld, lj, lane);
        cm = __shfl(ld, KNN);
    }
    int cnt = 0;

    const int qcx = cellof(me.x), qcy = cellof(me.y), qcz = cellof(me.z);
    const int qcell = spread4(qcx) | (spread4(qcy) << 1) | (spread4(qcz) << 2);

    // scan one cell's points (positions in init block excluded)
    #define SCAN_CELL(CELL)                                                     \
    {                                                                           \
        const int st = cstart[CELL];                                            \
        const int en = cstart[(CELL) + 1];                                      \
        for (int p = st; p < en; p += 64) {                                     \
            const int pos = p + lane;                                           \
            const bool in = (pos < en) && (pos < base || pos >= base + 64);     \
            const float4 pc = srt[min(pos, NPTS - 1)];                          \
            const float dx = me.x - pc.x, dy = me.y - pc.y, dz = me.z - pc.z;   \
            const float d = dx*dx + dy*dy + dz*dz;                              \
            const bool hit = in && (d < cm);                                    \
            const unsigned long long m = __ballot(hit);                         \
            if (m) {                                                            \
                const int tot = __popcll(m);                                    \
                if (cnt + tot > 64) {                                           \
                    compact(ld, lj, sd, sj, cnt, lane);                         \
                    cm = __shfl(ld, KNN);                                       \
                    cnt = 0;                                                    \
                }                                                               \
                const int below = __builtin_amdgcn_mbcnt_hi(                    \
                    (unsigned)(m >> 32),                                        \
                    __builtin_amdgcn_mbcnt_lo((unsigned)m, 0));                 \
                if (hit) { sd[cnt + below] = d; sj[cnt + below] = __float_as_int(pc.w); } \
                cnt += tot;                                                     \
            }                                                                   \
        }                                                                       \
    }

    SCAN_CELL(qcell);
    if (cnt > 0) { compact(ld, lj, sd, sj, cnt, lane); cm = __shfl(ld, KNN); cnt = 0; }

    // cell box from current radius
    const float r = sqrtf(cm);
    const int lox = cellof(me.x - r), hix = cellof(me.x + r);
    const int loy = cellof(me.y - r), hiy = cellof(me.y + r);
    const int loz = cellof(me.z - r), hiz = cellof(me.z + r);

    for (int cz = loz; cz <= hiz; ++cz) {
        const float z0 = (cz == 0)  ? -1e30f : GLO + (float)cz * GH;
        const float z1 = (cz == 15) ?  1e30f : GLO + (float)(cz + 1) * GH;
        float ddz = fmaxf(fmaxf(z0 - me.z, me.z - z1), 0.0f);
        ddz *= ddz;
        if (ddz >= cm) continue;
        const int mz = spread4(cz) << 2;
        for (int cy = loy; cy <= hiy; ++cy) {
            const float y0 = (cy == 0)  ? -1e30f : GLO + (float)cy * GH;
            const float y1 = (cy == 15) ?  1e30f : GLO + (float)(cy + 1) * GH;
            float ddy = fmaxf(fmaxf(y0 - me.y, me.y - y1), 0.0f);
            ddy = ddz + ddy * ddy;
            if (ddy >= cm) continue;
            const int myz = mz | (spread4(cy) << 1);
            for (int cx = lox; cx <= hix; ++cx) {
                if (cx == qcx && cy == qcy && cz == qcz) continue;
                const float x0 = (cx == 0)  ? -1e30f : GLO + (float)cx * GH;
                const float x1 = (cx == 15) ?  1e30f : GLO + (float)(cx + 1) * GH;
                float ddx = fmaxf(fmaxf(x0 - me.x, me.x - x1), 0.0f);
                ddx = ddy + ddx * ddx;
                if (ddx >= cm) continue;
                const int cell = myz | spread4(cx);
                SCAN_CELL(cell);
            }
        }
    }
    if (cnt > 0) compact(ld, lj, sd, sj, cnt, lane);
    #undef SCAN_CELL

    if (lane >= 1 && lane <= KNN) idx_out[qorig * KNN + lane - 1] = lj;
}

// ---------------- layer0 GEMM: K=3 special case ----------------
__global__ __launch_bounds__(128) void gemm0_kernel(const float* __restrict__ x,
                                                    const float* __restrict__ Wc,
                                                    float* __restrict__ T) {
    __shared__ float sw[384];
    const int t = threadIdx.x;
    sw[t]       = Wc[t];
    sw[t + 128] = Wc[t + 128];
    sw[t + 256] = Wc[t + 256];
    __syncthreads();
    const int n = blockIdx.x;
    const float x0 = x[3*n+0], x1 = x[3*n+1], x2 = x[3*n+2];
    T[n*128 + t] = x0*sw[3*t+0] + x1*sw[3*t+1] + x2*sw[3*t+2];
}

// ---------------- fp32 GEMM: T = H (NxK) * W^T (MxK) ----------------
#define BK 16
__global__ __launch_bounds__(256) void gemm_nt(const float* __restrict__ H,
                                               const float* __restrict__ W,
                                               float* __restrict__ T,
                                               int Kk, int Mm) {
    __shared__ float sH[BK][132];
    __shared__ float sW[BK][68];
    const int t  = threadIdx.x;
    const int rg = t & 15;
    const int cg = t >> 4;
    const int row0 = blockIdx.x * 128;
    const int col0 = blockIdx.y * 64;

    const int ar = t >> 2;
    const int ac = t & 3;

    float acc[8][4];
#pragma unroll
    for (int r = 0; r < 8; ++r)
#pragma unroll
        for (int c = 0; c < 4; ++c) acc[r][c] = 0.0f;

    for (int k0 = 0; k0 < Kk; k0 += BK) {
        const float4 ha = *reinterpret_cast<const float4*>(&H[(row0 + ar)      * Kk + k0 + ac*4]);
        const float4 hb = *reinterpret_cast<const float4*>(&H[(row0 + 64 + ar) * Kk + k0 + ac*4]);
        const float4 wa = *reinterpret_cast<const float4*>(&W[(col0 + ar)      * Kk + k0 + ac*4]);
        __syncthreads();
        sH[ac*4+0][ar]    = ha.x; sH[ac*4+1][ar]    = ha.y; sH[ac*4+2][ar]    = ha.z; sH[ac*4+3][ar]    = ha.w;
        sH[ac*4+0][64+ar] = hb.x; sH[ac*4+1][64+ar] = hb.y; sH[ac*4+2][64+ar] = hb.z; sH[ac*4+3][64+ar] = hb.w;
        sW[ac*4+0][ar]    = wa.x; sW[ac*4+1][ar]    = wa.y; sW[ac*4+2][ar]    = wa.z; sW[ac*4+3][ar]    = wa.w;
        __syncthreads();
#pragma unroll
        for (int kk = 0; kk < BK; ++kk) {
            const float4 a0 = *reinterpret_cast<const float4*>(&sH[kk][rg*4]);
            const float4 a1 = *reinterpret_cast<const float4*>(&sH[kk][64 + rg*4]);
            const float4 bv = *reinterpret_cast<const float4*>(&sW[kk][cg*4]);
            const float arr[8] = {a0.x, a0.y, a0.z, a0.w, a1.x, a1.y, a1.z, a1.w};
            const float bb[4]  = {bv.x, bv.y, bv.z, bv.w};
#pragma unroll
            for (int r = 0; r < 8; ++r)
#pragma unroll
                for (int c = 0; c < 4; ++c)
                    acc[r][c] = fmaf(arr[r], bb[c], acc[r][c]);
        }
    }
#pragma unroll
    for (int r = 0; r < 8; ++r) {
        const int row = (r < 4) ? (rg*4 + r) : (64 + rg*4 + (r - 4));
        *reinterpret_cast<float4*>(&T[(row0 + row)*Mm + col0 + cg*4]) =
            make_float4(acc[r][0], acc[r][1], acc[r][2], acc[r][3]);
    }
}

// ---------------- gather + max + bias + relu ----------------
template<int O>
__global__ __launch_bounds__(256) void maxrelu_kernel(const float* __restrict__ T,
                                                      const int* __restrict__ idx,
                                                      const float* __restrict__ bias,
                                                      float* __restrict__ out) {
    constexpr int PPB = 256 / O;
    constexpr int M2  = 2 * O;
    const int pi = threadIdx.x / O;
    const int o  = threadIdx.x & (O - 1);
    const int i  = blockIdx.x * PPB + pi;
    __shared__ int sidx[PPB * KNN];
    if (threadIdx.x < PPB * KNN)
        sidx[threadIdx.x] = idx[blockIdx.x * PPB * KNN + threadIdx.x];
    __syncthreads();
    const int sb = pi * KNN;
    float m = -INFINITY;
#pragma unroll
    for (int k = 0; k < KNN; ++k)
        m = fmaxf(m, T[sidx[sb + k] * M2 + O + o]);
    const float base = T[i * M2 + o] + bias[o];
    out[i * O + o] = fmaxf(base + m, 0.0f);
}

extern "C" void kernel_launch(void* const* d_in, const int* in_sizes, int n_in,
                              void* d_out, int out_size, void* d_ws, size_t ws_size,
                              hipStream_t stream) {
    const float* x  = (const float*)d_in[0];
    const float* W0 = (const float*)d_in[1];
    const float* b0 = (const float*)d_in[2];
    const float* W1 = (const float*)d_in[3];
    const float* b1 = (const float*)d_in[4];
    const float* W2 = (const float*)d_in[5];
    const float* b2 = (const float*)d_in[6];
    float* out = (float*)d_out;
    char*  ws  = (char*)d_ws;

    int*   idx  = (int*)(ws + 0);                 // 655360
    float* Wc0  = (float*)(ws + 655360);          // 1536
    float* Wc1  = (float*)(ws + 656896);          // 65536
    float* Wc2  = (float*)(ws + 722432);          // 262144
    float* bufA = (float*)(ws + 984576);          // 16 MB
    float* bufB = (float*)(ws + 17761792);        // 4 MB

    // knn-phase scratch aliases bufA (dead before gemm0 writes bufA)
    float4* xq     = (float4*)bufA;                       // 128 KB
    float4* srt    = (float4*)((char*)bufA + 131072);     // 128 KB
    int*    bId    = (int*)((char*)bufA + 262144);        // 32 KB
    int*    hist   = (int*)((char*)bufA + 294912);        // 16 KB
    int*    cstart = (int*)((char*)bufA + 311296);        // 16.4 KB
    int*    work   = (int*)((char*)bufA + 327712);        // 16 KB

    hipMemsetAsync(hist, 0, NCELL * sizeof(int), stream);
    prep_all<<<193, 256, 0, stream>>>(x, W0, W1, W2, xq, bId, hist, Wc0, Wc1, Wc2);
    prefix4096<<<1, 1024, 0, stream>>>(hist, cstart, work);
    scatter_pts<<<32, 256, 0, stream>>>(xq, bId, work, srt);
    knn_cell<<<NPTS / 4, 256, 0, stream>>>(srt, cstart, idx);

    gemm0_kernel<<<NPTS, 128, 0, stream>>>(x, Wc0, bufA);
    maxrelu_kernel<64><<<NPTS / 4, 256, 0, stream>>>(bufA, idx, b0, bufB);

    gemm_nt<<<dim3(64, 4), 256, 0, stream>>>(bufB, Wc1, bufA, 64, 256);
    maxrelu_kernel<128><<<NPTS / 2, 256, 0, stream>>>(bufA, idx, b1, bufB);

    gemm_nt<<<dim3(64, 8), 256, 0, stream>>>(bufB, Wc2, bufA, 128, 512);
    maxrelu_kernel<256><<<NPTS, 256, 0, stream>>>(bufA, idx, b2, out);
}

// Round 8
// 150.086 us; speedup vs baseline: 2.5103x; 2.5103x over previous
//
#include <hip/hip_runtime.h>
#include <math.h>

#define NPTS 8192
#define KNN  20
#define CHUNK 1024                 // knn: candidates staged per LDS chunk
#define NCHUNK (NPTS / CHUNK)      // 8

// 64-lane bitonic sort, ascending by lane. Keys d, payload ji.
__device__ __forceinline__ void bitonic64(float& d, int& ji, int lane) {
#pragma unroll
    for (int k = 2; k <= 64; k <<= 1) {
#pragma unroll
        for (int j = k >> 1; j > 0; j >>= 1) {
            const float od = __shfl_xor(d, j);
            const int   oi = __shfl_xor(ji, j);
            const bool up      = ((lane & k) == 0);
            const bool lower   = ((lane & j) == 0);
            const bool takeMin = (up == lower);
            const bool sw = takeMin ? (od < d) : (od > d);
            d  = sw ? od : d;
            ji = sw ? oi : ji;
        }
    }
}

// clean a bitonic 64-sequence into ascending order
__device__ __forceinline__ void bitonic_clean64(float& d, int& ji, int lane) {
#pragma unroll
    for (int j = 32; j > 0; j >>= 1) {
        const float od = __shfl_xor(d, j);
        const int   oi = __shfl_xor(ji, j);
        const bool lower = ((lane & j) == 0);
        const bool sw = lower ? (od < d) : (od > d);
        d  = sw ? od : d;
        ji = sw ? oi : ji;
    }
}

// merge LDS hit-pool (cnt entries) into the resident sorted-64 list (ld,lj)
__device__ __forceinline__ void compact(float& ld, int& lj,
                                        const float* __restrict__ sd,
                                        const int* __restrict__ sj,
                                        int cnt, int lane) {
    __builtin_amdgcn_wave_barrier();          // order pool ds_writes before reads
    float bd = (lane < cnt) ? sd[lane] : INFINITY;
    int   bj = (lane < cnt) ? sj[lane] : -1;
    bitonic64(bd, bj, lane);
    const float rd = __shfl(bd, 63 - lane);
    const int   rj = __shfl(bj, 63 - lane);
    const bool sw = rd < ld;
    float md = sw ? rd : ld;
    int   mj = sw ? rj : lj;
    bitonic_clean64(md, mj, lane);
    ld = md; lj = mj;
}

// ---------------- KNN: top-20 nearest (excl. self) ----------------
// 1 query/wave, 4 waves/block, 2048 blocks. Candidates staged via 16 KB LDS
// chunks. Init top-64 from query's OWN aligned 64-block (contains self, d=0);
// that batch is nulled in the main loop (scalar check, no per-lane self test).
// Main loop: 4 batches in flight (4x ds_read_b128 -> 4x distance -> 4x ballot
// -> one rare-path) for memory-level parallelism. Hits appended lane-parallel
// to a 64-slot LDS pool; bitonic compaction on overflow. Lazy cm is exact
// (stale cm >= true cm; extras auto-dropped). Output lanes 1..20 (lane 0=self).
__global__ __launch_bounds__(256) void knn_kernel(const float4* __restrict__ xq,
                                                  int* __restrict__ idx_out) {
    __shared__ float4 sxq[CHUNK];
    __shared__ float  sdp[4][64];
    __shared__ int    sjp[4][64];
    const int lane = threadIdx.x & 63;
    const int wv   = threadIdx.x >> 6;
    const int q    = blockIdx.x * 4 + wv;
    float* sd = sdp[wv];
    int*   sj = sjp[wv];

    const float4 p = xq[q];
    const int base = q & ~63;                 // own aligned 64-block

    // init: own block (contains self, d=0 -> lane 0 after sort)
    float ld, cm;
    int lj;
    {
        const float4 c = xq[base + lane];
        const float dx = p.x - c.x, dy = p.y - c.y, dz = p.z - c.z;
        ld = dx*dx + dy*dy + dz*dz;
        lj = base + lane;
        bitonic64(ld, lj, lane);
        cm = __shfl(ld, KNN);                 // 21st incl self = 20th excl
    }
    int cnt = 0;

    for (int c = 0; c < NCHUNK; ++c) {
        __syncthreads();   // protect previous chunk's reads
#pragma unroll
        for (int u = 0; u < CHUNK / 256; ++u)
            sxq[u * 256 + threadIdx.x] = xq[c * CHUNK + u * 256 + threadIdx.x];
        __syncthreads();

        const int cbase = c * CHUNK;
        for (int g = 0; g < 4; ++g) {         // 4 groups x 4 batches x 64
            const int b0 = g * 4;
            const float4 c0 = sxq[(b0+0)*64 + lane];
            const float4 c1 = sxq[(b0+1)*64 + lane];
            const float4 c2 = sxq[(b0+2)*64 + lane];
            const float4 c3 = sxq[(b0+3)*64 + lane];
            const float dx0 = p.x-c0.x, dy0 = p.y-c0.y, dz0 = p.z-c0.z;
            const float dx1 = p.x-c1.x, dy1 = p.y-c1.y, dz1 = p.z-c1.z;
            const float dx2 = p.x-c2.x, dy2 = p.y-c2.y, dz2 = p.z-c2.z;
            const float dx3 = p.x-c3.x, dy3 = p.y-c3.y, dz3 = p.z-c3.z;
            const float d0 = dx0*dx0 + dy0*dy0 + dz0*dz0;
            const float d1 = dx1*dx1 + dy1*dy1 + dz1*dz1;
            const float d2 = dx2*dx2 + dy2*dy2 + dz2*dz2;
            const float d3 = dx3*dx3 + dy3*dy3 + dz3*dz3;
            const int jb0 = cbase + (b0+0)*64;
            const int jb1 = cbase + (b0+1)*64;
            const int jb2 = cbase + (b0+2)*64;
            const int jb3 = cbase + (b0+3)*64;
            unsigned long long m0 = __ballot(d0 < cm);
            unsigned long long m1 = __ballot(d1 < cm);
            unsigned long long m2 = __ballot(d2 < cm);
            unsigned long long m3 = __ballot(d3 < cm);
            if (jb0 == base) m0 = 0;          // own block already in init
            if (jb1 == base) m1 = 0;
            if (jb2 == base) m2 = 0;
            if (jb3 == base) m3 = 0;
            if (m0 | m1 | m2 | m3) {
#define HANDLE(M, D, JB)                                                      \
                if (M) {                                                      \
                    const int tot = __popcll(M);                              \
                    if (cnt + tot > 64) {                                     \
                        compact(ld, lj, sd, sj, cnt, lane);                   \
                        cm = __shfl(ld, KNN);                                 \
                        cnt = 0;                                              \
                    }                                                         \
                    const int below = __builtin_amdgcn_mbcnt_hi(              \
                        (unsigned)((M) >> 32),                                \
                        __builtin_amdgcn_mbcnt_lo((unsigned)(M), 0));         \
                    const bool h = ((M) >> lane) & 1ull;                      \
                    if (h) { sd[cnt + below] = D; sj[cnt + below] = (JB) + lane; } \
                    cnt += tot;                                               \
                }
                HANDLE(m0, d0, jb0)
                HANDLE(m1, d1, jb1)
                HANDLE(m2, d2, jb2)
                HANDLE(m3, d3, jb3)
#undef HANDLE
            }
        }
    }
    if (cnt > 0) compact(ld, lj, sd, sj, cnt, lane);

    if (lane >= 1 && lane <= KNN) idx_out[q * KNN + lane - 1] = lj;
}

// ---------------- fused prep: xq + Wc0 + Wc1 + Wc2 ----------------
__device__ __forceinline__ void prep_w_elem(const float* __restrict__ W,
                                            float* __restrict__ Wc,
                                            int tid, int O, int C) {
    const int o = tid / C, k = tid % C;
    const float wa = W[o*2*C + k];
    const float wb = W[o*2*C + C + k];
    Wc[o*C + k]       = wa - wb;
    Wc[(O + o)*C + k] = wb;
}

__global__ void prep_all(const float* __restrict__ x,
                         const float* __restrict__ W0,
                         const float* __restrict__ W1,
                         const float* __restrict__ W2,
                         float4* __restrict__ xq,
                         float* __restrict__ Wc0,
                         float* __restrict__ Wc1,
                         float* __restrict__ Wc2) {
    const int bid = blockIdx.x;
    const int t = threadIdx.x;
    if (bid < 32) {
        const int i = bid * 256 + t;
        xq[i] = make_float4(x[3*i+0], x[3*i+1], x[3*i+2], 0.0f);
    } else if (bid == 32) {
        if (t < 192) prep_w_elem(W0, Wc0, t, 64, 3);
    } else if (bid < 65) {
        prep_w_elem(W1, Wc1, (bid - 33) * 256 + t, 128, 64);
    } else {
        prep_w_elem(W2, Wc2, (bid - 65) * 256 + t, 256, 128);
    }
}

// ---------------- layer0 GEMM: K=3 special case ----------------
__global__ __launch_bounds__(128) void gemm0_kernel(const float* __restrict__ x,
                                                    const float* __restrict__ Wc,
                                                    float* __restrict__ T) {
    __shared__ float sw[384];
    const int t = threadIdx.x;
    sw[t]       = Wc[t];
    sw[t + 128] = Wc[t + 128];
    sw[t + 256] = Wc[t + 256];
    __syncthreads();
    const int n = blockIdx.x;
    const float x0 = x[3*n+0], x1 = x[3*n+1], x2 = x[3*n+2];
    T[n*128 + t] = x0*sw[3*t+0] + x1*sw[3*t+1] + x2*sw[3*t+2];
}

// ---------------- fp32 GEMM: T = H (NxK) * W^T (MxK) ----------------
#define BK 16
__global__ __launch_bounds__(256) void gemm_nt(const float* __restrict__ H,
                                               const float* __restrict__ W,
                                               float* __restrict__ T,
                                               int Kk, int Mm) {
    __shared__ float sH[BK][132];
    __shared__ float sW[BK][68];
    const int t  = threadIdx.x;
    const int rg = t & 15;
    const int cg = t >> 4;
    const int row0 = blockIdx.x * 128;
    const int col0 = blockIdx.y * 64;

    const int ar = t >> 2;
    const int ac = t & 3;

    float acc[8][4];
#pragma unroll
    for (int r = 0; r < 8; ++r)
#pragma unroll
        for (int c = 0; c < 4; ++c) acc[r][c] = 0.0f;

    for (int k0 = 0; k0 < Kk; k0 += BK) {
        const float4 ha = *reinterpret_cast<const float4*>(&H[(row0 + ar)      * Kk + k0 + ac*4]);
        const float4 hb = *reinterpret_cast<const float4*>(&H[(row0 + 64 + ar) * Kk + k0 + ac*4]);
        const float4 wa = *reinterpret_cast<const float4*>(&W[(col0 + ar)      * Kk + k0 + ac*4]);
        __syncthreads();
        sH[ac*4+0][ar]    = ha.x; sH[ac*4+1][ar]    = ha.y; sH[ac*4+2][ar]    = ha.z; sH[ac*4+3][ar]    = ha.w;
        sH[ac*4+0][64+ar] = hb.x; sH[ac*4+1][64+ar] = hb.y; sH[ac*4+2][64+ar] = hb.z; sH[ac*4+3][64+ar] = hb.w;
        sW[ac*4+0][ar]    = wa.x; sW[ac*4+1][ar]    = wa.y; sW[ac*4+2][ar]    = wa.z; sW[ac*4+3][ar]    = wa.w;
        __syncthreads();
#pragma unroll
        for (int kk = 0; kk < BK; ++kk) {
            const float4 a0 = *reinterpret_cast<const float4*>(&sH[kk][rg*4]);
            const float4 a1 = *reinterpret_cast<const float4*>(&sH[kk][64 + rg*4]);
            const float4 bv = *reinterpret_cast<const float4*>(&sW[kk][cg*4]);
            const float arr[8] = {a0.x, a0.y, a0.z, a0.w, a1.x, a1.y, a1.z, a1.w};
            const float bb[4]  = {bv.x, bv.y, bv.z, bv.w};
#pragma unroll
            for (int r = 0; r < 8; ++r)
#pragma unroll
                for (int c = 0; c < 4; ++c)
                    acc[r][c] = fmaf(arr[r], bb[c], acc[r][c]);
        }
    }
#pragma unroll
    for (int r = 0; r < 8; ++r) {
        const int row = (r < 4) ? (rg*4 + r) : (64 + rg*4 + (r - 4));
        *reinterpret_cast<float4*>(&T[(row0 + row)*Mm + col0 + cg*4]) =
            make_float4(acc[r][0], acc[r][1], acc[r][2], acc[r][3]);
    }
}

// ---------------- gather + max + bias + relu ----------------
template<int O>
__global__ __launch_bounds__(256) void maxrelu_kernel(const float* __restrict__ T,
                                                      const int* __restrict__ idx,
                                                      const float* __restrict__ bias,
                                                      float* __restrict__ out) {
    constexpr int PPB = 256 / O;
    constexpr int M2  = 2 * O;
    const int pi = threadIdx.x / O;
    const int o  = threadIdx.x & (O - 1);
    const int i  = blockIdx.x * PPB + pi;
    __shared__ int sidx[PPB * KNN];
    if (threadIdx.x < PPB * KNN)
        sidx[threadIdx.x] = idx[blockIdx.x * PPB * KNN + threadIdx.x];
    __syncthreads();
    const int sb = pi * KNN;
    float m = -INFINITY;
#pragma unroll
    for (int k = 0; k < KNN; ++k)
        m = fmaxf(m, T[sidx[sb + k] * M2 + O + o]);
    const float base = T[i * M2 + o] + bias[o];
    out[i * O + o] = fmaxf(base + m, 0.0f);
}

extern "C" void kernel_launch(void* const* d_in, const int* in_sizes, int n_in,
                              void* d_out, int out_size, void* d_ws, size_t ws_size,
                              hipStream_t stream) {
    const float* x  = (const float*)d_in[0];
    const float* W0 = (const float*)d_in[1];
    const float* b0 = (const float*)d_in[2];
    const float* W1 = (const float*)d_in[3];
    const float* b1 = (const float*)d_in[4];
    const float* W2 = (const float*)d_in[5];
    const float* b2 = (const float*)d_in[6];
    float* out = (float*)d_out;
    char*  ws  = (char*)d_ws;

    int*   idx  = (int*)(ws + 0);                 // 8192*20*4   = 655360
    float* Wc0  = (float*)(ws + 655360);          // 1536
    float* Wc1  = (float*)(ws + 656896);          // 65536
    float* Wc2  = (float*)(ws + 722432);          // 262144
    float* bufA = (float*)(ws + 984576);          // 8192*512*4  = 16777216
    float* bufB = (float*)(ws + 17761792);        // 8192*128*4  = 4194304
    float4* xq  = (float4*)bufA;  // aliases bufA; knn done before gemm0 writes

    prep_all<<<193, 256, 0, stream>>>(x, W0, W1, W2, xq, Wc0, Wc1, Wc2);

    knn_kernel<<<NPTS / 4, 256, 0, stream>>>(xq, idx);

    gemm0_kernel<<<NPTS, 128, 0, stream>>>(x, Wc0, bufA);
    maxrelu_kernel<64><<<NPTS / 4, 256, 0, stream>>>(bufA, idx, b0, bufB);

    gemm_nt<<<dim3(64, 4), 256, 0, stream>>>(bufB, Wc1, bufA, 64, 256);
    maxrelu_kernel<128><<<NPTS / 2, 256, 0, stream>>>(bufA, idx, b1, bufB);

    gemm_nt<<<dim3(64, 8), 256, 0, stream>>>(bufB, Wc2, bufA, 128, 512);
    maxrelu_kernel<256><<<NPTS, 256, 0, stream>>>(bufA, idx, b2, out);
}